// Round 18
// baseline (169.542 us; speedup 1.0000x reference)
//
#include <hip/hip_runtime.h>
#include <hip/hip_bf16.h>

#define D_ 128
#define E_ 100
#define K_ 4
#define C_ 400
#define MB 256         // atoms per k_dist block
#define NCHUNK 128     // atom chunks in k_sums3 (x2 dim-halves = 256 blocks)
#define SCALE 65536.0f
#define INV_SCALE (1.0f / 65536.0f)
#define CNSCALE 4096.0f
#define INV_CNSCALE (1.0f / 4096.0f)

// ws layout (f32/i32 slots):
#define OFF_COUNTS 51200
#define OFF_LOSS   51600
#define OFF_PSUM   51712
#define PSUM_SZ    (256 * C_ * 64)
#define OFF_PCNT   (OFF_PSUM + PSUM_SZ)
#define WS_NEED_PART ((size_t)(OFF_PCNT + NCHUNK * C_) * 4)

typedef _Float16 f16x8 __attribute__((ext_vector_type(8)));
typedef float f32x4v __attribute__((ext_vector_type(4)));

template <int CTRL>
__device__ __forceinline__ unsigned dpp_minu(unsigned x) {
  unsigned y = (unsigned)__builtin_amdgcn_update_dpp(0, (int)x, CTRL, 0xF, 0xF, true);
  return x < y ? x : y;
}

// MFMA brute-force distance kernel. Block = 1024 thr (16 waves) x 256 atoms.
// cb staged ONCE per block into LDS as fp16 (XOR-swizzled rows); each wave
// owns 16 atoms x all 400 codes via 25 16x16x32 MFMA tiles; argmin tracked
// as packed (d2|col) running-min per lane, 4-step DPP-min at the end.
// Writes hq (from LDS fp16), at, loss.
__global__ __launch_bounds__(1024) void k_dist(
    const float* __restrict__ h, const int* __restrict__ ei,
    const float* __restrict__ cb, float* __restrict__ hq,
    float* __restrict__ at, float* __restrict__ loss_acc, int N) {
  __shared__ __align__(16) unsigned cbls[C_ * 64];  // fp16 codebook, swizzled
  __shared__ int cnormI[C_];
  __shared__ float wl[16];
  const int tid = threadIdx.x;

  // phase 0: stage codebook (f32 -> fp16, swizzle) + ||c||^2 (s32 fixed-pt)
  if (tid < C_) cnormI[tid] = 0;
  __syncthreads();
  {
    const float4* cb4 = (const float4*)cb;
    for (int idx = tid; idx < C_ * 32; idx += 1024) {
      int code = idx >> 5, kq = idx & 31;
      float4 f = cb4[code * 32 + kq];
      unsigned short q0 = __builtin_bit_cast(unsigned short, (_Float16)f.x);
      unsigned short q1 = __builtin_bit_cast(unsigned short, (_Float16)f.y);
      unsigned short q2 = __builtin_bit_cast(unsigned short, (_Float16)f.z);
      unsigned short q3 = __builtin_bit_cast(unsigned short, (_Float16)f.w);
      int i = (code * 64 + kq * 2) ^ ((code & 7) << 2);
      cbls[i]     = (unsigned)q0 | ((unsigned)q1 << 16);
      cbls[i + 1] = (unsigned)q2 | ((unsigned)q3 << 16);
      float sq = f.x * f.x + f.y * f.y + f.z * f.z + f.w * f.w;
      atomicAdd(&cnormI[code], __float2int_rn(sq * CNSCALE));
    }
  }
  __syncthreads();

  const int w = tid >> 6, l = tid & 63;
  const int row = l & 15, g = l >> 4;       // row: atom (phase1/2) / k-chunk (phase3)
  const int abase = blockIdx.x * MB + w * 16;
  const float4* h4 = (const float4*)h;

  // phase 1: A fragments (h -> fp16 regs) + ||h||^2 + element ids
  const int aload = min(abase + row, N - 1);
  int e = ei[aload];
  float hn = 0.f;
  f16x8 af0, af1, af2, af3;
#define LOADA(K, AF) { \
    float4 u = h4[(size_t)aload * 32 + (K) * 8 + g * 2]; \
    float4 v = h4[(size_t)aload * 32 + (K) * 8 + g * 2 + 1]; \
    AF[0]=(_Float16)u.x; AF[1]=(_Float16)u.y; AF[2]=(_Float16)u.z; AF[3]=(_Float16)u.w; \
    AF[4]=(_Float16)v.x; AF[5]=(_Float16)v.y; AF[6]=(_Float16)v.z; AF[7]=(_Float16)v.w; \
    hn += u.x*u.x + u.y*u.y + u.z*u.z + u.w*u.w \
        + v.x*v.x + v.y*v.y + v.z*v.z + v.w*v.w; }
  LOADA(0, af0) LOADA(1, af1) LOADA(2, af2) LOADA(3, af3)
#undef LOADA
  hn += __shfl_xor(hn, 16, 64);
  hn += __shfl_xor(hn, 32, 64);
  const int ec0 = 4 * __shfl(e, g * 4 + 0, 64), ec1 = 4 * __shfl(e, g * 4 + 1, 64),
            ec2 = 4 * __shfl(e, g * 4 + 2, 64), ec3 = 4 * __shfl(e, g * 4 + 3, 64);
  const float hn0 = __shfl(hn, g * 4 + 0, 64), hn1 = __shfl(hn, g * 4 + 1, 64),
              hn2 = __shfl(hn, g * 4 + 2, 64), hn3 = __shfl(hn, g * 4 + 3, 64);

  // phase 2: 25 tiles of 16 codes; running packed min per lane
  const unsigned sx = (unsigned)((row & 7) << 2);   // (c&7)==(row&7) since t*16%8==0
  unsigned b0 = 0x7F800000u, b1 = 0x7F800000u, b2 = 0x7F800000u, b3 = 0x7F800000u;
  for (int t = 0; t < 25; ++t) {
    const int c = t * 16 + row;
    const int ib = c * 64 + g * 4;
    f32x4v acc = {0.f, 0.f, 0.f, 0.f};
    uint4 r0 = *(const uint4*)&cbls[(unsigned)ib ^ sx];
    acc = __builtin_amdgcn_mfma_f32_16x16x32_f16(af0, __builtin_bit_cast(f16x8, r0), acc, 0, 0, 0);
    uint4 r1 = *(const uint4*)&cbls[(unsigned)(ib + 16) ^ sx];
    acc = __builtin_amdgcn_mfma_f32_16x16x32_f16(af1, __builtin_bit_cast(f16x8, r1), acc, 0, 0, 0);
    uint4 r2 = *(const uint4*)&cbls[(unsigned)(ib + 32) ^ sx];
    acc = __builtin_amdgcn_mfma_f32_16x16x32_f16(af2, __builtin_bit_cast(f16x8, r2), acc, 0, 0, 0);
    uint4 r3 = *(const uint4*)&cbls[(unsigned)(ib + 48) ^ sx];
    acc = __builtin_amdgcn_mfma_f32_16x16x32_f16(af3, __builtin_bit_cast(f16x8, r3), acc, 0, 0, 0);
    const float cnf = (float)cnormI[c] * INV_CNSCALE;
#define STEP(J, BJ, ECJ, HNJ) { \
    float d = fmaxf(HNJ - 2.f * acc[J] + cnf, 0.f); \
    unsigned key = (__builtin_bit_cast(unsigned, d) & 0xFFFFFE00u) | (unsigned)c; \
    key = ((unsigned)(c - (ECJ)) < 4u) ? key : 0x7F800000u; \
    BJ = BJ < key ? BJ : key; }
    STEP(0, b0, ec0, hn0) STEP(1, b1, ec1, hn1)
    STEP(2, b2, ec2, hn2) STEP(3, b3, ec3, hn3)
#undef STEP
  }
  // 16-lane min reduce (cols live on lanes 0-15 of each group)
  b0 = dpp_minu<0xB1>(b0); b0 = dpp_minu<0x4E>(b0); b0 = dpp_minu<0x141>(b0); b0 = dpp_minu<0x140>(b0);
  b1 = dpp_minu<0xB1>(b1); b1 = dpp_minu<0x4E>(b1); b1 = dpp_minu<0x141>(b1); b1 = dpp_minu<0x140>(b1);
  b2 = dpp_minu<0xB1>(b2); b2 = dpp_minu<0x4E>(b2); b2 = dpp_minu<0x141>(b2); b2 = dpp_minu<0x140>(b2);
  b3 = dpp_minu<0xB1>(b3); b3 = dpp_minu<0x4E>(b3); b3 = dpp_minu<0x141>(b3); b3 = dpp_minu<0x140>(b3);

  // phase 3: outputs. group g owns rows g*4+J; lane's k-chunk = row (=l&15).
  float4* hq4 = (float4*)hq;
  float loss = 0.f;
#define OUTJ(J, BJ) { \
    const int colj = (int)((BJ) & 0x1FFu); \
    const int rloc = g * 4 + (J); \
    if (abase + rloc < N) { \
      const size_t arow = (size_t)(abase + rloc); \
      const unsigned swj = (unsigned)((colj & 7) << 2); \
      uint4 raw = *(const uint4*)&cbls[(unsigned)(colj * 64 + row * 4) ^ swj]; \
      f16x8 cv = __builtin_bit_cast(f16x8, raw); \
      float4 o1 = make_float4((float)cv[0], (float)cv[1], (float)cv[2], (float)cv[3]); \
      float4 o2 = make_float4((float)cv[4], (float)cv[5], (float)cv[6], (float)cv[7]); \
      hq4[arow * 32 + row * 2]     = o1; \
      hq4[arow * 32 + row * 2 + 1] = o2; \
      if (row == 0) { \
        at[arow] = (float)colj; \
        loss += __builtin_bit_cast(float, (BJ) & 0xFFFFFE00u); \
      } } }
  OUTJ(0, b0) OUTJ(1, b1) OUTJ(2, b2) OUTJ(3, b3)
#undef OUTJ

  loss += __shfl_xor(loss, 16, 64);
  loss += __shfl_xor(loss, 32, 64);
  if (l == 0) wl[w] = loss;
  __syncthreads();
  if (tid == 0) {
    float s = 0.f;
#pragma unroll
    for (int i = 0; i < 16; ++i) s += wl[i];
    atomicAdd(loss_acc, s);
  }
}

// Kernel 2: streaming segment-sum + counts with NATIVE s32 LDS atomics.
__global__ __launch_bounds__(1024) void k_sums3(
    const float* __restrict__ h, const float* __restrict__ at,
    int* __restrict__ psumI, int* __restrict__ pcntI,
    float* __restrict__ sums, float* __restrict__ countsF,
    int dopart, int N) {
  const int half = blockIdx.x & 1;
  const int chunk = blockIdx.x >> 1;
  __shared__ int acc[C_ * 64];
  __shared__ int cnt[C_];
  for (int i = threadIdx.x; i < C_ * 64; i += 1024) acc[i] = 0;
  if (half == 0)
    for (int i = threadIdx.x; i < C_; i += 1024) cnt[i] = 0;
  __syncthreads();

  const int per = (N + NCHUNK - 1) / NCHUNK;
  const int a0 = chunk * per;
  const int aEnd = min(a0 + per, N);
  const int w = threadIdx.x >> 6;
  const int lane = threadIdx.x & 63;
  const int g = lane >> 4, t = lane & 15;
  const float4* h4 = (const float4*)h;

  int a = a0 + w * 4 + g;
  bool ok0 = a < aEnd, ok1 = (a + 64) < aEnd;
  float4 v0 = {}, v1 = {}; int c0 = 0, c1 = 0;
  if (ok0) { v0 = h4[(size_t)a * 32 + half * 16 + t]; c0 = (int)at[a]; }
  if (ok1) { v1 = h4[(size_t)(a + 64) * 32 + half * 16 + t]; c1 = (int)at[a + 64]; }

  while (ok0) {
    const int an = a + 128;
    const bool okn = an < aEnd;
    float4 vn = {}; int cn = 0;
    if (okn) { vn = h4[(size_t)an * 32 + half * 16 + t]; cn = (int)at[an]; }

    int* ap = &acc[c0 * 64 + t * 4];
    int iv0 = __float2int_rn(v0.x * SCALE);
    int iv1 = __float2int_rn(v0.y * SCALE);
    int iv2 = __float2int_rn(v0.z * SCALE);
    int iv3 = __float2int_rn(v0.w * SCALE);
    if (g == 0) { atomicAdd(&ap[0],iv0); atomicAdd(&ap[1],iv1); atomicAdd(&ap[2],iv2); atomicAdd(&ap[3],iv3); }
    else if (g == 1) { atomicAdd(&ap[1],iv1); atomicAdd(&ap[2],iv2); atomicAdd(&ap[3],iv3); atomicAdd(&ap[0],iv0); }
    else if (g == 2) { atomicAdd(&ap[2],iv2); atomicAdd(&ap[3],iv3); atomicAdd(&ap[0],iv0); atomicAdd(&ap[1],iv1); }
    else { atomicAdd(&ap[3],iv3); atomicAdd(&ap[0],iv0); atomicAdd(&ap[1],iv1); atomicAdd(&ap[2],iv2); }
    if (half == 0 && t == 0) atomicAdd(&cnt[c0], 1);

    a += 64;
    ok0 = ok1; v0 = v1; c0 = c1;
    ok1 = okn; v1 = vn; c1 = cn;
  }
  __syncthreads();

  if (dopart) {
    int* pb = psumI + (size_t)blockIdx.x * (C_ * 64);
    for (int i = threadIdx.x; i < C_ * 64; i += 1024) pb[i] = acc[i];
    if (half == 0) {
      int* pc = pcntI + (size_t)chunk * C_;
      for (int i = threadIdx.x; i < C_; i += 1024) pc[i] = cnt[i];
    }
  } else {
    for (int i = threadIdx.x; i < C_ * 64; i += 1024) {
      int vv = acc[i];
      if (vv != 0)
        atomicAdd(&sums[(size_t)(i >> 6) * D_ + half * 64 + (i & 63)],
                  (float)vv * INV_SCALE);
    }
    if (half == 0)
      for (int i = threadIdx.x; i < C_; i += 1024)
        if (cnt[i] != 0) atomicAdd(&countsF[i], (float)cnt[i]);
  }
}

// Kernel 3 (partials path): reduce s32 partials -> f32 sums, countsF.
__global__ __launch_bounds__(256) void k_reduce(
    const int* __restrict__ psumI, const int* __restrict__ pcntI,
    float* __restrict__ sums, float* __restrict__ countsF) {
  int idx = blockIdx.x * 256 + threadIdx.x;
  if (idx < C_ * D_) {
    int code = idx >> 7;
    int dim = idx & 127;
    int half = dim >> 6;
    int dl = dim & 63;
    const int* p = psumI + (size_t)half * (C_ * 64) + code * 64 + dl;
    float s = 0.f;
    for (int b = 0; b < NCHUNK; ++b)
      s += (float)p[(size_t)b * 2 * (C_ * 64)];
    sums[idx] = s * INV_SCALE;
  }
  if (idx < C_) {
    int s = 0;
    for (int b = 0; b < NCHUNK; ++b)
      s += pcntI[(size_t)b * C_ + idx];
    countsF[idx] = (float)s;
  }
}

// Kernel 4: EMA finalize + loss scalar.
__global__ __launch_bounds__(256) void k_final(
    const float* __restrict__ cb, const float* __restrict__ ecnt,
    const float* __restrict__ esum, const float* __restrict__ ws,
    float* __restrict__ out, int N) {
  const float* sums = ws;
  const float* countsF = ws + OFF_COUNTS;
  int idx = blockIdx.x * 256 + threadIdx.x;
  const size_t base = (size_t)N * D_ + N + 1;
  if (idx < C_ * D_) {
    int c = idx >> 7;
    int e4 = (c >> 2) << 2;
    bool present = (countsF[e4] + countsF[e4 + 1] + countsF[e4 + 2] + countsF[e4 + 3]) > 0.f;
    float es = esum[idx];
    float s  = sums[idx];
    float ns = present ? 0.99f * es + 0.01f * s : es;
    float ec = ecnt[c];
    float nc = present ? 0.99f * ec + 0.01f * countsF[c] : ec;
    float ncbv = present ? ns / fmaxf(nc, 1e-5f) : cb[idx];
    out[base + idx] = ncbv;
    if ((idx & 127) == 0) out[base + C_ * D_ + c] = nc;
    out[base + C_ * D_ + C_ + idx] = ns;
  }
  if (idx == 0) {
    float loss = ws[OFF_LOSS];
    out[(size_t)N * D_ + N] = 0.25f * loss / ((float)N * (float)D_);
  }
}

extern "C" void kernel_launch(void* const* d_in, const int* in_sizes, int n_in,
                              void* d_out, int out_size, void* d_ws, size_t ws_size,
                              hipStream_t stream) {
  // Identify inputs by size (robust to input-order changes).
  const float* h = nullptr; const int* ei = nullptr;
  const float* cb = nullptr; const float* ecnt = nullptr; const float* esum = nullptr;
  long hsz = -1; int hidx = -1;
  for (int i = 0; i < n_in; ++i)
    if ((long)in_sizes[i] > hsz) { hsz = in_sizes[i]; hidx = i; }
  h = (const float*)d_in[hidx];
  const int N = (int)(hsz / D_);
  for (int i = 0; i < n_in; ++i) {
    if (i == hidx) continue;
    const int s = in_sizes[i];
    if (s == N) ei = (const int*)d_in[i];
    else if (s == C_) ecnt = (const float*)d_in[i];
    else if (s == C_ * D_) { if (!cb) cb = (const float*)d_in[i]; else esum = (const float*)d_in[i]; }
  }

  float* out = (float*)d_out;
  float* hq  = out;
  float* at  = out + (size_t)N * D_;

  float* ws = (float*)d_ws;
  float* sums    = ws;
  float* countsF = ws + OFF_COUNTS;
  float* lossp   = ws + OFF_LOSS;
  int*   psumI   = (int*)(ws + OFF_PSUM);
  int*   pcntI   = (int*)(ws + OFF_PCNT);

  const int dopart = (ws_size >= WS_NEED_PART) ? 1 : 0;

  // zero sums/countsF/loss; psum partials fully overwritten
  hipMemsetAsync(d_ws, 0, (size_t)(OFF_LOSS + 1) * 4, stream);

  const int nblk = (N + MB - 1) / MB;
  k_dist<<<nblk, 1024, 0, stream>>>(h, ei, cb, hq, at, lossp, N);
  k_sums3<<<NCHUNK * 2, 1024, 0, stream>>>(h, at, psumI, pcntI,
                                           sums, countsF, dopart, N);
  if (dopart)
    k_reduce<<<(C_ * D_ + 255) / 256, 256, 0, stream>>>(psumI, pcntI, sums, countsF);
  k_final<<<(C_ * D_ + 255) / 256, 256, 0, stream>>>(cb, ecnt, esum, ws, out, N);
}

// Round 19
// 106.445 us; speedup vs baseline: 1.5928x; 1.5928x over previous
//
#include <hip/hip_runtime.h>
#include <hip/hip_bf16.h>

#define D_ 128
#define E_ 100
#define K_ 4
#define C_ 400
#define NCHUNK 128     // atom chunks in k_sums3 (x2 dim-halves = 256 blocks)
#define SCALE 65536.0f
#define INV_SCALE (1.0f / 65536.0f)

// ws layout (f32/i32 slots):
#define OFF_COUNTS 51200
#define OFF_LOSS   51600
#define OFF_PSUM   51712
#define PSUM_SZ    (256 * C_ * 64)
#define OFF_PCNT   (OFF_PSUM + PSUM_SZ)
#define WS_NEED_PART ((size_t)(OFF_PCNT + NCHUNK * C_) * 4)

template <int CTRL>
__device__ __forceinline__ float dpp_add(float x) {
  int y = __builtin_amdgcn_update_dpp(0, __builtin_bit_cast(int, x),
                                      CTRL, 0xF, 0xF, true);
  return x + __builtin_bit_cast(float, y);
}

__device__ __forceinline__ float dist8(float4 hA, float4 hB, float4 cA, float4 cB) {
  float d0 = hA.x - cA.x, d1 = hA.y - cA.y;
  float d2 = hA.z - cA.z, d3 = hA.w - cA.w;
  float d4 = hB.x - cB.x, d5 = hB.y - cB.y;
  float d6 = hB.z - cB.z, d7 = hB.w - cB.w;
  return ((d0*d0 + d1*d1) + (d2*d2 + d3*d3)) +
         ((d4*d4 + d5*d5) + (d6*d6 + d7*d7));
}

// Kernel 1: streaming argmin, 16 lanes/atom, dense-halves layout.
// DUAL DEPENDENCE CHAINS: each group processes TWO adjacent atoms per
// iteration with fully duplicated named-scalar register sets (~120 VGPR).
// While atom x's cross-lane DPP join drains, atom y's 8 cb loads remain
// outstanding. 1-deep h/ei prefetch for the next pair.
__global__ __launch_bounds__(256) void k_assign(
    const float* __restrict__ h, const int* __restrict__ ei,
    const float* __restrict__ cb, float* __restrict__ hq,
    float* __restrict__ at, float* __restrict__ loss_acc, int N) {
  const int t = threadIdx.x & 15;
  const int gid = (blockIdx.x * 256 + threadIdx.x) >> 4;
  const int ng = (gridDim.x * 256) >> 4;
  const float4* h4 = (const float4*)h;
  const float4* cb4 = (const float4*)cb;
  float4* hq4 = (float4*)hq;
  float loss = 0.f;

  int ax = gid * 2;                  // pair base (N is even)
  const int stride = ng * 2;
  bool ok = ax < N;
  const int as0 = ok ? ax : 0;
  int ex = ei[as0];
  int ey = ei[as0 + 1];
  float4 hAx = h4[(size_t)as0 * 32 + t];
  float4 hBx = h4[(size_t)as0 * 32 + 16 + t];
  float4 hAy = h4[(size_t)(as0 + 1) * 32 + t];
  float4 hBy = h4[(size_t)(as0 + 1) * 32 + 16 + t];

  while (ok) {
    const int an = ax + stride;
    const bool okn = an < N;
    const int ans = okn ? an : ax;
    // prefetch next pair (clamped, always issued)
    const int exn = ei[ans];
    const int eyn = ei[ans + 1];
    const float4 hAxn = h4[(size_t)ans * 32 + t];
    const float4 hBxn = h4[(size_t)ans * 32 + 16 + t];
    const float4 hAyn = h4[(size_t)(ans + 1) * 32 + t];
    const float4 hByn = h4[(size_t)(ans + 1) * 32 + 16 + t];

    // issue BOTH atoms' cb loads before either join
    const size_t cx = (size_t)ex * 128 + t;
    const float4 xA0 = cb4[cx],      xB0 = cb4[cx + 16];
    const float4 xA1 = cb4[cx + 32], xB1 = cb4[cx + 48];
    const float4 xA2 = cb4[cx + 64], xB2 = cb4[cx + 80];
    const float4 xA3 = cb4[cx + 96], xB3 = cb4[cx + 112];
    const size_t cy = (size_t)ey * 128 + t;
    const float4 yA0 = cb4[cy],      yB0 = cb4[cy + 16];
    const float4 yA1 = cb4[cy + 32], yB1 = cb4[cy + 48];
    const float4 yA2 = cb4[cy + 64], yB2 = cb4[cy + 80];
    const float4 yA3 = cb4[cy + 96], yB3 = cb4[cy + 112];

    float px0 = dist8(hAx, hBx, xA0, xB0);
    float px1 = dist8(hAx, hBx, xA1, xB1);
    float px2 = dist8(hAx, hBx, xA2, xB2);
    float px3 = dist8(hAx, hBx, xA3, xB3);
    float py0 = dist8(hAy, hBy, yA0, yB0);
    float py1 = dist8(hAy, hBy, yA1, yB1);
    float py2 = dist8(hAy, hBy, yA2, yB2);
    float py3 = dist8(hAy, hBy, yA3, yB3);

    // 8 independent DPP butterfly chains, interleaved
    px0 = dpp_add<0xB1>(px0); px1 = dpp_add<0xB1>(px1);
    px2 = dpp_add<0xB1>(px2); px3 = dpp_add<0xB1>(px3);
    py0 = dpp_add<0xB1>(py0); py1 = dpp_add<0xB1>(py1);
    py2 = dpp_add<0xB1>(py2); py3 = dpp_add<0xB1>(py3);
    px0 = dpp_add<0x4E>(px0); px1 = dpp_add<0x4E>(px1);
    px2 = dpp_add<0x4E>(px2); px3 = dpp_add<0x4E>(px3);
    py0 = dpp_add<0x4E>(py0); py1 = dpp_add<0x4E>(py1);
    py2 = dpp_add<0x4E>(py2); py3 = dpp_add<0x4E>(py3);
    px0 = dpp_add<0x141>(px0); px1 = dpp_add<0x141>(px1);
    px2 = dpp_add<0x141>(px2); px3 = dpp_add<0x141>(px3);
    py0 = dpp_add<0x141>(py0); py1 = dpp_add<0x141>(py1);
    py2 = dpp_add<0x141>(py2); py3 = dpp_add<0x141>(py3);
    px0 = dpp_add<0x140>(px0); px1 = dpp_add<0x140>(px1);
    px2 = dpp_add<0x140>(px2); px3 = dpp_add<0x140>(px3);
    py0 = dpp_add<0x140>(py0); py1 = dpp_add<0x140>(py1);
    py2 = dpp_add<0x140>(py2); py3 = dpp_add<0x140>(py3);

    int bx = 0; float bpx = px0;
    if (px1 < bpx) { bpx = px1; bx = 1; }
    if (px2 < bpx) { bpx = px2; bx = 2; }
    if (px3 < bpx) { bpx = px3; bx = 3; }
    int by = 0; float bpy = py0;
    if (py1 < bpy) { bpy = py1; by = 1; }
    if (py2 < bpy) { bpy = py2; by = 2; }
    if (py3 < bpy) { bpy = py3; by = 3; }

    float4 qAx = xA0, qBx = xB0;
    if (bx == 1) { qAx = xA1; qBx = xB1; }
    if (bx == 2) { qAx = xA2; qBx = xB2; }
    if (bx == 3) { qAx = xA3; qBx = xB3; }
    float4 qAy = yA0, qBy = yB0;
    if (by == 1) { qAy = yA1; qBy = yB1; }
    if (by == 2) { qAy = yA2; qBy = yB2; }
    if (by == 3) { qAy = yA3; qBy = yB3; }

    hq4[(size_t)ax * 32 + t]            = qAx;
    hq4[(size_t)ax * 32 + 16 + t]       = qBx;
    hq4[(size_t)(ax + 1) * 32 + t]      = qAy;
    hq4[(size_t)(ax + 1) * 32 + 16 + t] = qBy;
    if (t == 0) {
      at[ax]     = (float)(ex * K_ + bx);
      at[ax + 1] = (float)(ey * K_ + by);
      loss += bpx + bpy;
    }

    ax = an; ok = okn;
    ex = exn; ey = eyn;
    hAx = hAxn; hBx = hBxn; hAy = hAyn; hBy = hByn;
  }

  // block loss reduction via shuffles (loss lives on lanes 0,16,32,48)
  loss += __shfl_xor(loss, 16, 64);
  loss += __shfl_xor(loss, 32, 64);
  __shared__ float wl[4];
  const int w = threadIdx.x >> 6;
  if ((threadIdx.x & 63) == 0) wl[w] = loss;
  __syncthreads();
  if (threadIdx.x == 0)
    atomicAdd(loss_acc, wl[0] + wl[1] + wl[2] + wl[3]);
}

// Kernel 2: streaming segment-sum + counts with NATIVE s32 LDS atomics.
__global__ __launch_bounds__(1024) void k_sums3(
    const float* __restrict__ h, const float* __restrict__ at,
    int* __restrict__ psumI, int* __restrict__ pcntI,
    float* __restrict__ sums, float* __restrict__ countsF,
    int dopart, int N) {
  const int half = blockIdx.x & 1;
  const int chunk = blockIdx.x >> 1;
  __shared__ int acc[C_ * 64];
  __shared__ int cnt[C_];
  for (int i = threadIdx.x; i < C_ * 64; i += 1024) acc[i] = 0;
  if (half == 0)
    for (int i = threadIdx.x; i < C_; i += 1024) cnt[i] = 0;
  __syncthreads();

  const int per = (N + NCHUNK - 1) / NCHUNK;
  const int a0 = chunk * per;
  const int aEnd = min(a0 + per, N);
  const int w = threadIdx.x >> 6;
  const int lane = threadIdx.x & 63;
  const int g = lane >> 4, t = lane & 15;
  const float4* h4 = (const float4*)h;

  int a = a0 + w * 4 + g;
  bool ok0 = a < aEnd, ok1 = (a + 64) < aEnd;
  float4 v0 = {}, v1 = {}; int c0 = 0, c1 = 0;
  if (ok0) { v0 = h4[(size_t)a * 32 + half * 16 + t]; c0 = (int)at[a]; }
  if (ok1) { v1 = h4[(size_t)(a + 64) * 32 + half * 16 + t]; c1 = (int)at[a + 64]; }

  while (ok0) {
    const int an = a + 128;
    const bool okn = an < aEnd;
    float4 vn = {}; int cn = 0;
    if (okn) { vn = h4[(size_t)an * 32 + half * 16 + t]; cn = (int)at[an]; }

    int* ap = &acc[c0 * 64 + t * 4];
    int iv0 = __float2int_rn(v0.x * SCALE);
    int iv1 = __float2int_rn(v0.y * SCALE);
    int iv2 = __float2int_rn(v0.z * SCALE);
    int iv3 = __float2int_rn(v0.w * SCALE);
    if (g == 0) { atomicAdd(&ap[0],iv0); atomicAdd(&ap[1],iv1); atomicAdd(&ap[2],iv2); atomicAdd(&ap[3],iv3); }
    else if (g == 1) { atomicAdd(&ap[1],iv1); atomicAdd(&ap[2],iv2); atomicAdd(&ap[3],iv3); atomicAdd(&ap[0],iv0); }
    else if (g == 2) { atomicAdd(&ap[2],iv2); atomicAdd(&ap[3],iv3); atomicAdd(&ap[0],iv0); atomicAdd(&ap[1],iv1); }
    else { atomicAdd(&ap[3],iv3); atomicAdd(&ap[0],iv0); atomicAdd(&ap[1],iv1); atomicAdd(&ap[2],iv2); }
    if (half == 0 && t == 0) atomicAdd(&cnt[c0], 1);

    a += 64;
    ok0 = ok1; v0 = v1; c0 = c1;
    ok1 = okn; v1 = vn; c1 = cn;
  }
  __syncthreads();

  if (dopart) {
    int* pb = psumI + (size_t)blockIdx.x * (C_ * 64);
    for (int i = threadIdx.x; i < C_ * 64; i += 1024) pb[i] = acc[i];
    if (half == 0) {
      int* pc = pcntI + (size_t)chunk * C_;
      for (int i = threadIdx.x; i < C_; i += 1024) pc[i] = cnt[i];
    }
  } else {
    for (int i = threadIdx.x; i < C_ * 64; i += 1024) {
      int vv = acc[i];
      if (vv != 0)
        atomicAdd(&sums[(size_t)(i >> 6) * D_ + half * 64 + (i & 63)],
                  (float)vv * INV_SCALE);
    }
    if (half == 0)
      for (int i = threadIdx.x; i < C_; i += 1024)
        if (cnt[i] != 0) atomicAdd(&countsF[i], (float)cnt[i]);
  }
}

// Kernel 3 (partials path): reduce s32 partials -> f32 sums, countsF.
__global__ __launch_bounds__(256) void k_reduce(
    const int* __restrict__ psumI, const int* __restrict__ pcntI,
    float* __restrict__ sums, float* __restrict__ countsF) {
  int idx = blockIdx.x * 256 + threadIdx.x;
  if (idx < C_ * D_) {
    int code = idx >> 7;
    int dim = idx & 127;
    int half = dim >> 6;
    int dl = dim & 63;
    const int* p = psumI + (size_t)half * (C_ * 64) + code * 64 + dl;
    float s = 0.f;
    for (int b = 0; b < NCHUNK; ++b)
      s += (float)p[(size_t)b * 2 * (C_ * 64)];
    sums[idx] = s * INV_SCALE;
  }
  if (idx < C_) {
    int s = 0;
    for (int b = 0; b < NCHUNK; ++b)
      s += pcntI[(size_t)b * C_ + idx];
    countsF[idx] = (float)s;
  }
}

// Kernel 4: EMA finalize + loss scalar.
__global__ __launch_bounds__(256) void k_final(
    const float* __restrict__ cb, const float* __restrict__ ecnt,
    const float* __restrict__ esum, const float* __restrict__ ws,
    float* __restrict__ out, int N) {
  const float* sums = ws;
  const float* countsF = ws + OFF_COUNTS;
  int idx = blockIdx.x * 256 + threadIdx.x;
  const size_t base = (size_t)N * D_ + N + 1;
  if (idx < C_ * D_) {
    int c = idx >> 7;
    int e4 = (c >> 2) << 2;
    bool present = (countsF[e4] + countsF[e4 + 1] + countsF[e4 + 2] + countsF[e4 + 3]) > 0.f;
    float es = esum[idx];
    float s  = sums[idx];
    float ns = present ? 0.99f * es + 0.01f * s : es;
    float ec = ecnt[c];
    float nc = present ? 0.99f * ec + 0.01f * countsF[c] : ec;
    float ncbv = present ? ns / fmaxf(nc, 1e-5f) : cb[idx];
    out[base + idx] = ncbv;
    if ((idx & 127) == 0) out[base + C_ * D_ + c] = nc;
    out[base + C_ * D_ + C_ + idx] = ns;
  }
  if (idx == 0) {
    float loss = ws[OFF_LOSS];
    out[(size_t)N * D_ + N] = 0.25f * loss / ((float)N * (float)D_);
  }
}

extern "C" void kernel_launch(void* const* d_in, const int* in_sizes, int n_in,
                              void* d_out, int out_size, void* d_ws, size_t ws_size,
                              hipStream_t stream) {
  // Identify inputs by size (robust to input-order changes).
  const float* h = nullptr; const int* ei = nullptr;
  const float* cb = nullptr; const float* ecnt = nullptr; const float* esum = nullptr;
  long hsz = -1; int hidx = -1;
  for (int i = 0; i < n_in; ++i)
    if ((long)in_sizes[i] > hsz) { hsz = in_sizes[i]; hidx = i; }
  h = (const float*)d_in[hidx];
  const int N = (int)(hsz / D_);
  for (int i = 0; i < n_in; ++i) {
    if (i == hidx) continue;
    const int s = in_sizes[i];
    if (s == N) ei = (const int*)d_in[i];
    else if (s == C_) ecnt = (const float*)d_in[i];
    else if (s == C_ * D_) { if (!cb) cb = (const float*)d_in[i]; else esum = (const float*)d_in[i]; }
  }

  float* out = (float*)d_out;
  float* hq  = out;
  float* at  = out + (size_t)N * D_;

  float* ws = (float*)d_ws;
  float* sums    = ws;
  float* countsF = ws + OFF_COUNTS;
  float* lossp   = ws + OFF_LOSS;
  int*   psumI   = (int*)(ws + OFF_PSUM);
  int*   pcntI   = (int*)(ws + OFF_PCNT);

  const int dopart = (ws_size >= WS_NEED_PART) ? 1 : 0;

  // zero sums/countsF/loss; psum partials fully overwritten
  hipMemsetAsync(d_ws, 0, (size_t)(OFF_LOSS + 1) * 4, stream);

  k_assign<<<1024, 256, 0, stream>>>(h, ei, cb, hq, at, lossp, N);
  k_sums3<<<NCHUNK * 2, 1024, 0, stream>>>(h, at, psumI, pcntI,
                                           sums, countsF, dopart, N);
  if (dopart)
    k_reduce<<<(C_ * D_ + 255) / 256, 256, 0, stream>>>(psumI, pcntI, sums, countsF);
  k_final<<<(C_ * D_ + 255) / 256, 256, 0, stream>>>(cb, ecnt, esum, ws, out, N);
}

// Round 21
// 95.877 us; speedup vs baseline: 1.7683x; 1.1102x over previous
//
#include <hip/hip_runtime.h>
#include <hip/hip_bf16.h>

#define D_ 128
#define E_ 100
#define K_ 4
#define C_ 400
#define NCHUNK 128     // atom chunks in k_sums3 (x2 dim-halves = 256 blocks)
#define SCALE 65536.0f
#define INV_SCALE (1.0f / 65536.0f)

// ws layout (f32/i32 slots):
#define OFF_COUNTS 51200
#define OFF_LOSS   51600
#define OFF_PSUM   51712
#define PSUM_SZ    (256 * C_ * 64)
#define OFF_PCNT   (OFF_PSUM + PSUM_SZ)
#define WS_NEED_PART ((size_t)(OFF_PCNT + NCHUNK * C_) * 4)

typedef float f32x4 __attribute__((ext_vector_type(4)));

__device__ __forceinline__ void nt_store4(float4 v, float4* p) {
  __builtin_nontemporal_store(__builtin_bit_cast(f32x4, v), (f32x4*)p);
}

template <int CTRL>
__device__ __forceinline__ float dpp_add(float x) {
  int y = __builtin_amdgcn_update_dpp(0, __builtin_bit_cast(int, x),
                                      CTRL, 0xF, 0xF, true);
  return x + __builtin_bit_cast(float, y);
}

__device__ __forceinline__ float dist8(float4 hA, float4 hB, float4 cA, float4 cB) {
  float d0 = hA.x - cA.x, d1 = hA.y - cA.y;
  float d2 = hA.z - cA.z, d3 = hA.w - cA.w;
  float d4 = hB.x - cB.x, d5 = hB.y - cB.y;
  float d6 = hB.z - cB.z, d7 = hB.w - cB.w;
  return ((d0*d0 + d1*d1) + (d2*d2 + d3*d3)) +
         ((d4*d4 + d5*d5) + (d6*d6 + d7*d7));
}

// Kernel 1: streaming argmin, 16 lanes/atom, dense-halves layout.
// Dual dependence chains (2 adjacent atoms/group/iter) + grid 2048
// (8 blocks/CU) for TLP, + NON-TEMPORAL hq stores (hq is never re-read;
// keep L3 for h).
__global__ __launch_bounds__(256) void k_assign(
    const float* __restrict__ h, const int* __restrict__ ei,
    const float* __restrict__ cb, float* __restrict__ hq,
    float* __restrict__ at, float* __restrict__ loss_acc, int N) {
  const int t = threadIdx.x & 15;
  const int gid = (blockIdx.x * 256 + threadIdx.x) >> 4;
  const int ng = (gridDim.x * 256) >> 4;
  const float4* h4 = (const float4*)h;
  const float4* cb4 = (const float4*)cb;
  float4* hq4 = (float4*)hq;
  float loss = 0.f;

  int ax = gid * 2;                  // pair base (N is even)
  const int stride = ng * 2;
  bool ok = ax < N;
  const int as0 = ok ? ax : 0;
  int ex = ei[as0];
  int ey = ei[as0 + 1];
  float4 hAx = h4[(size_t)as0 * 32 + t];
  float4 hBx = h4[(size_t)as0 * 32 + 16 + t];
  float4 hAy = h4[(size_t)(as0 + 1) * 32 + t];
  float4 hBy = h4[(size_t)(as0 + 1) * 32 + 16 + t];

  while (ok) {
    const int an = ax + stride;
    const bool okn = an < N;
    const int ans = okn ? an : ax;
    // prefetch next pair (clamped, always issued)
    const int exn = ei[ans];
    const int eyn = ei[ans + 1];
    const float4 hAxn = h4[(size_t)ans * 32 + t];
    const float4 hBxn = h4[(size_t)ans * 32 + 16 + t];
    const float4 hAyn = h4[(size_t)(ans + 1) * 32 + t];
    const float4 hByn = h4[(size_t)(ans + 1) * 32 + 16 + t];

    // issue BOTH atoms' cb loads before either join
    const size_t cx = (size_t)ex * 128 + t;
    const float4 xA0 = cb4[cx],      xB0 = cb4[cx + 16];
    const float4 xA1 = cb4[cx + 32], xB1 = cb4[cx + 48];
    const float4 xA2 = cb4[cx + 64], xB2 = cb4[cx + 80];
    const float4 xA3 = cb4[cx + 96], xB3 = cb4[cx + 112];
    const size_t cy = (size_t)ey * 128 + t;
    const float4 yA0 = cb4[cy],      yB0 = cb4[cy + 16];
    const float4 yA1 = cb4[cy + 32], yB1 = cb4[cy + 48];
    const float4 yA2 = cb4[cy + 64], yB2 = cb4[cy + 80];
    const float4 yA3 = cb4[cy + 96], yB3 = cb4[cy + 112];

    float px0 = dist8(hAx, hBx, xA0, xB0);
    float px1 = dist8(hAx, hBx, xA1, xB1);
    float px2 = dist8(hAx, hBx, xA2, xB2);
    float px3 = dist8(hAx, hBx, xA3, xB3);
    float py0 = dist8(hAy, hBy, yA0, yB0);
    float py1 = dist8(hAy, hBy, yA1, yB1);
    float py2 = dist8(hAy, hBy, yA2, yB2);
    float py3 = dist8(hAy, hBy, yA3, yB3);

    // 8 independent DPP butterfly chains, interleaved
    px0 = dpp_add<0xB1>(px0); px1 = dpp_add<0xB1>(px1);
    px2 = dpp_add<0xB1>(px2); px3 = dpp_add<0xB1>(px3);
    py0 = dpp_add<0xB1>(py0); py1 = dpp_add<0xB1>(py1);
    py2 = dpp_add<0xB1>(py2); py3 = dpp_add<0xB1>(py3);
    px0 = dpp_add<0x4E>(px0); px1 = dpp_add<0x4E>(px1);
    px2 = dpp_add<0x4E>(px2); px3 = dpp_add<0x4E>(px3);
    py0 = dpp_add<0x4E>(py0); py1 = dpp_add<0x4E>(py1);
    py2 = dpp_add<0x4E>(py2); py3 = dpp_add<0x4E>(py3);
    px0 = dpp_add<0x141>(px0); px1 = dpp_add<0x141>(px1);
    px2 = dpp_add<0x141>(px2); px3 = dpp_add<0x141>(px3);
    py0 = dpp_add<0x141>(py0); py1 = dpp_add<0x141>(py1);
    py2 = dpp_add<0x141>(py2); py3 = dpp_add<0x141>(py3);
    px0 = dpp_add<0x140>(px0); px1 = dpp_add<0x140>(px1);
    px2 = dpp_add<0x140>(px2); px3 = dpp_add<0x140>(px3);
    py0 = dpp_add<0x140>(py0); py1 = dpp_add<0x140>(py1);
    py2 = dpp_add<0x140>(py2); py3 = dpp_add<0x140>(py3);

    int bx = 0; float bpx = px0;
    if (px1 < bpx) { bpx = px1; bx = 1; }
    if (px2 < bpx) { bpx = px2; bx = 2; }
    if (px3 < bpx) { bpx = px3; bx = 3; }
    int by = 0; float bpy = py0;
    if (py1 < bpy) { bpy = py1; by = 1; }
    if (py2 < bpy) { bpy = py2; by = 2; }
    if (py3 < bpy) { bpy = py3; by = 3; }

    float4 qAx = xA0, qBx = xB0;
    if (bx == 1) { qAx = xA1; qBx = xB1; }
    if (bx == 2) { qAx = xA2; qBx = xB2; }
    if (bx == 3) { qAx = xA3; qBx = xB3; }
    float4 qAy = yA0, qBy = yB0;
    if (by == 1) { qAy = yA1; qBy = yB1; }
    if (by == 2) { qAy = yA2; qBy = yB2; }
    if (by == 3) { qAy = yA3; qBy = yB3; }

    nt_store4(qAx, &hq4[(size_t)ax * 32 + t]);
    nt_store4(qBx, &hq4[(size_t)ax * 32 + 16 + t]);
    nt_store4(qAy, &hq4[(size_t)(ax + 1) * 32 + t]);
    nt_store4(qBy, &hq4[(size_t)(ax + 1) * 32 + 16 + t]);
    if (t == 0) {
      at[ax]     = (float)(ex * K_ + bx);
      at[ax + 1] = (float)(ey * K_ + by);
      loss += bpx + bpy;
    }

    ax = an; ok = okn;
    ex = exn; ey = eyn;
    hAx = hAxn; hBx = hBxn; hAy = hAyn; hBy = hByn;
  }

  // block loss reduction via shuffles (loss lives on lanes 0,16,32,48)
  loss += __shfl_xor(loss, 16, 64);
  loss += __shfl_xor(loss, 32, 64);
  __shared__ float wl[4];
  const int w = threadIdx.x >> 6;
  if ((threadIdx.x & 63) == 0) wl[w] = loss;
  __syncthreads();
  if (threadIdx.x == 0)
    atomicAdd(loss_acc, wl[0] + wl[1] + wl[2] + wl[3]);
}

// Kernel 2: streaming segment-sum + counts with NATIVE s32 LDS atomics.
__global__ __launch_bounds__(1024) void k_sums3(
    const float* __restrict__ h, const float* __restrict__ at,
    int* __restrict__ psumI, int* __restrict__ pcntI,
    float* __restrict__ sums, float* __restrict__ countsF,
    int dopart, int N) {
  const int half = blockIdx.x & 1;
  const int chunk = blockIdx.x >> 1;
  __shared__ int acc[C_ * 64];
  __shared__ int cnt[C_];
  for (int i = threadIdx.x; i < C_ * 64; i += 1024) acc[i] = 0;
  if (half == 0)
    for (int i = threadIdx.x; i < C_; i += 1024) cnt[i] = 0;
  __syncthreads();

  const int per = (N + NCHUNK - 1) / NCHUNK;
  const int a0 = chunk * per;
  const int aEnd = min(a0 + per, N);
  const int w = threadIdx.x >> 6;
  const int lane = threadIdx.x & 63;
  const int g = lane >> 4, t = lane & 15;
  const float4* h4 = (const float4*)h;

  int a = a0 + w * 4 + g;
  bool ok0 = a < aEnd, ok1 = (a + 64) < aEnd;
  float4 v0 = {}, v1 = {}; int c0 = 0, c1 = 0;
  if (ok0) { v0 = h4[(size_t)a * 32 + half * 16 + t]; c0 = (int)at[a]; }
  if (ok1) { v1 = h4[(size_t)(a + 64) * 32 + half * 16 + t]; c1 = (int)at[a + 64]; }

  while (ok0) {
    const int an = a + 128;
    const bool okn = an < aEnd;
    float4 vn = {}; int cn = 0;
    if (okn) { vn = h4[(size_t)an * 32 + half * 16 + t]; cn = (int)at[an]; }

    int* ap = &acc[c0 * 64 + t * 4];
    int iv0 = __float2int_rn(v0.x * SCALE);
    int iv1 = __float2int_rn(v0.y * SCALE);
    int iv2 = __float2int_rn(v0.z * SCALE);
    int iv3 = __float2int_rn(v0.w * SCALE);
    if (g == 0) { atomicAdd(&ap[0],iv0); atomicAdd(&ap[1],iv1); atomicAdd(&ap[2],iv2); atomicAdd(&ap[3],iv3); }
    else if (g == 1) { atomicAdd(&ap[1],iv1); atomicAdd(&ap[2],iv2); atomicAdd(&ap[3],iv3); atomicAdd(&ap[0],iv0); }
    else if (g == 2) { atomicAdd(&ap[2],iv2); atomicAdd(&ap[3],iv3); atomicAdd(&ap[0],iv0); atomicAdd(&ap[1],iv1); }
    else { atomicAdd(&ap[3],iv3); atomicAdd(&ap[0],iv0); atomicAdd(&ap[1],iv1); atomicAdd(&ap[2],iv2); }
    if (half == 0 && t == 0) atomicAdd(&cnt[c0], 1);

    a += 64;
    ok0 = ok1; v0 = v1; c0 = c1;
    ok1 = okn; v1 = vn; c1 = cn;
  }
  __syncthreads();

  if (dopart) {
    int* pb = psumI + (size_t)blockIdx.x * (C_ * 64);
    for (int i = threadIdx.x; i < C_ * 64; i += 1024) pb[i] = acc[i];
    if (half == 0) {
      int* pc = pcntI + (size_t)chunk * C_;
      for (int i = threadIdx.x; i < C_; i += 1024) pc[i] = cnt[i];
    }
  } else {
    for (int i = threadIdx.x; i < C_ * 64; i += 1024) {
      int vv = acc[i];
      if (vv != 0)
        atomicAdd(&sums[(size_t)(i >> 6) * D_ + half * 64 + (i & 63)],
                  (float)vv * INV_SCALE);
    }
    if (half == 0)
      for (int i = threadIdx.x; i < C_; i += 1024)
        if (cnt[i] != 0) atomicAdd(&countsF[i], (float)cnt[i]);
  }
}

// Kernel 3 (partials path): reduce s32 partials -> f32 sums, countsF.
__global__ __launch_bounds__(256) void k_reduce(
    const int* __restrict__ psumI, const int* __restrict__ pcntI,
    float* __restrict__ sums, float* __restrict__ countsF) {
  int idx = blockIdx.x * 256 + threadIdx.x;
  if (idx < C_ * D_) {
    int code = idx >> 7;
    int dim = idx & 127;
    int half = dim >> 6;
    int dl = dim & 63;
    const int* p = psumI + (size_t)half * (C_ * 64) + code * 64 + dl;
    float s = 0.f;
    for (int b = 0; b < NCHUNK; ++b)
      s += (float)p[(size_t)b * 2 * (C_ * 64)];
    sums[idx] = s * INV_SCALE;
  }
  if (idx < C_) {
    int s = 0;
    for (int b = 0; b < NCHUNK; ++b)
      s += pcntI[(size_t)b * C_ + idx];
    countsF[idx] = (float)s;
  }
}

// Kernel 4: EMA finalize + loss scalar.
__global__ __launch_bounds__(256) void k_final(
    const float* __restrict__ cb, const float* __restrict__ ecnt,
    const float* __restrict__ esum, const float* __restrict__ ws,
    float* __restrict__ out, int N) {
  const float* sums = ws;
  const float* countsF = ws + OFF_COUNTS;
  int idx = blockIdx.x * 256 + threadIdx.x;
  const size_t base = (size_t)N * D_ + N + 1;
  if (idx < C_ * D_) {
    int c = idx >> 7;
    int e4 = (c >> 2) << 2;
    bool present = (countsF[e4] + countsF[e4 + 1] + countsF[e4 + 2] + countsF[e4 + 3]) > 0.f;
    float es = esum[idx];
    float s  = sums[idx];
    float ns = present ? 0.99f * es + 0.01f * s : es;
    float ec = ecnt[c];
    float nc = present ? 0.99f * ec + 0.01f * countsF[c] : ec;
    float ncbv = present ? ns / fmaxf(nc, 1e-5f) : cb[idx];
    out[base + idx] = ncbv;
    if ((idx & 127) == 0) out[base + C_ * D_ + c] = nc;
    out[base + C_ * D_ + C_ + idx] = ns;
  }
  if (idx == 0) {
    float loss = ws[OFF_LOSS];
    out[(size_t)N * D_ + N] = 0.25f * loss / ((float)N * (float)D_);
  }
}

extern "C" void kernel_launch(void* const* d_in, const int* in_sizes, int n_in,
                              void* d_out, int out_size, void* d_ws, size_t ws_size,
                              hipStream_t stream) {
  // Identify inputs by size (robust to input-order changes).
  const float* h = nullptr; const int* ei = nullptr;
  const float* cb = nullptr; const float* ecnt = nullptr; const float* esum = nullptr;
  long hsz = -1; int hidx = -1;
  for (int i = 0; i < n_in; ++i)
    if ((long)in_sizes[i] > hsz) { hsz = in_sizes[i]; hidx = i; }
  h = (const float*)d_in[hidx];
  const int N = (int)(hsz / D_);
  for (int i = 0; i < n_in; ++i) {
    if (i == hidx) continue;
    const int s = in_sizes[i];
    if (s == N) ei = (const int*)d_in[i];
    else if (s == C_) ecnt = (const float*)d_in[i];
    else if (s == C_ * D_) { if (!cb) cb = (const float*)d_in[i]; else esum = (const float*)d_in[i]; }
  }

  float* out = (float*)d_out;
  float* hq  = out;
  float* at  = out + (size_t)N * D_;

  float* ws = (float*)d_ws;
  float* sums    = ws;
  float* countsF = ws + OFF_COUNTS;
  float* lossp   = ws + OFF_LOSS;
  int*   psumI   = (int*)(ws + OFF_PSUM);
  int*   pcntI   = (int*)(ws + OFF_PCNT);

  const int dopart = (ws_size >= WS_NEED_PART) ? 1 : 0;

  // zero sums/countsF/loss; psum partials fully overwritten
  hipMemsetAsync(d_ws, 0, (size_t)(OFF_LOSS + 1) * 4, stream);

  k_assign<<<2048, 256, 0, stream>>>(h, ei, cb, hq, at, lossp, N);
  k_sums3<<<NCHUNK * 2, 1024, 0, stream>>>(h, at, psumI, pcntI,
                                           sums, countsF, dopart, N);
  if (dopart)
    k_reduce<<<(C_ * D_ + 255) / 256, 256, 0, stream>>>(psumI, pcntI, sums, countsF);
  k_final<<<(C_ * D_ + 255) / 256, 256, 0, stream>>>(cb, ecnt, esum, ws, out, N);
}